// Round 9
// baseline (280.060 us; speedup 1.0000x reference)
//
#include <hip/hip_runtime.h>
#include <stdint.h>

// ---------------------------------------------------------------------------
// MultiHeadAttention fwd: out = softmax((xWq)(xWk)^T / 8) (xWv) @ Wo
// B=4, N=2048, H=16, Dk=64, Dmodel=1024.  bf16 MFMA 16x16x32 everywhere.
// R9: 8-phase GEMM re-pipelined to the m201 order: each phase reads the
// NEXT quadrant's fragments so ds_read latency hides under the current
// quadrant's 16 MFMAs.  vmcnt(4) per phase confirms exactly the unit read.
// Attn unchanged.
// ---------------------------------------------------------------------------

#define NSEQ   2048
#define BQ     4
#define NTOK   (BQ * NSEQ)      // 8192
#define DMODEL 1024
#define DK     64
#define HEADS  16

using bf16x8 = __attribute__((ext_vector_type(8))) short;           // 8 bf16 raw
using u16x8  = __attribute__((ext_vector_type(8))) unsigned short;
using u16x4  = __attribute__((ext_vector_type(4))) unsigned short;
using f32x4  = __attribute__((ext_vector_type(4))) float;

#define AS1C(p) ((const __attribute__((address_space(1))) void*)(p))
#define AS3(p)  ((__attribute__((address_space(3))) void*)(p))

__device__ __forceinline__ unsigned short f2bf(float f) {
    unsigned int u = __float_as_uint(f);
    u += 0x7FFFu + ((u >> 16) & 1u);     // RNE
    return (unsigned short)(u >> 16);
}

// ------------------------------- conversions -------------------------------

__global__ __launch_bounds__(256) void cvt_x_kernel(const float4* __restrict__ in,
                                                    u16x4* __restrict__ out) {
    int idx = blockIdx.x * 256 + threadIdx.x;   // exact: 8192*256*4 == 8.39M
    float4 v = in[idx];
    u16x4 o;
    o[0] = f2bf(v.x); o[1] = f2bf(v.y); o[2] = f2bf(v.z); o[3] = f2bf(v.w);
    out[idx] = o;
}

// in: fp32 [K][Nn] row-major  ->  out: bf16 [Nn][K] row-major (i.e. W^T)
__global__ __launch_bounds__(256) void transpose_cvt_kernel(const float* __restrict__ in,
                                                            unsigned short* __restrict__ out,
                                                            int K, int Nn) {
    __shared__ float t[32][33];
    int c0 = blockIdx.x * 32;     // Nn tile
    int r0 = blockIdx.y * 32;     // K tile
    int tx = threadIdx.x;         // 0..31
    int ty = threadIdx.y;         // 0..7
#pragma unroll
    for (int i = 0; i < 4; i++) {
        int r = ty + i * 8;
        t[r][tx] = in[(size_t)(r0 + r) * Nn + c0 + tx];
    }
    __syncthreads();
#pragma unroll
    for (int i = 0; i < 4; i++) {
        int r = ty + i * 8;
        out[(size_t)(c0 + r) * K + r0 + tx] = f2bf(t[tx][r]);
    }
}

// --------------------------- 8-phase 256x256 GEMM --------------------------
// C[M,N] = A[M,K] * BT[N,K]^T, K=1024.  8 waves (2M x 4N), per-wave 128x64.
// LDS 128KB: 2 dbuf x { A [2 units] | B [2 units] }, 16KB units.  XOR
// swizzle slot^(idx&7), pre-applied to the global source column.
// Per phase: stage 1 unit -> vmcnt(4) -> barrier -> ds_read NEXT quad's
// fragments (hide under MFMA) -> setprio(1) 16 MFMA setprio(0) -> barrier.
// Read schedule: Ph1 reads a2(t), Ph2 b2(t), Ph3 none, Ph4 a1,b1(t+1).
// vmcnt(4) at each staging phase retires exactly the unit read that phase
// (outstanding: 6,6,6,8 at Ph1..Ph4 wait points).
template <int MO, int NO>
__device__ __forceinline__ void quad(f32x4 (&acc)[8][4], const bf16x8 (&a)[4][2],
                                     const bf16x8 (&b)[2][2]) {
    __builtin_amdgcn_s_setprio(1);
#pragma unroll
    for (int mf = 0; mf < 4; mf++)
#pragma unroll
        for (int nf = 0; nf < 2; nf++)
#pragma unroll
            for (int kk = 0; kk < 2; kk++)
                acc[MO + mf][NO + nf] = __builtin_amdgcn_mfma_f32_16x16x32_bf16(
                    a[mf][kk], b[nf][kk], acc[MO + mf][NO + nf], 0, 0, 0);
    __builtin_amdgcn_s_setprio(0);
}

__device__ __forceinline__ void readA(bf16x8 (&dst)[4][2], const char* cb, int uoff,
                                      const int (&base)[2]) {
#pragma unroll
    for (int mf = 0; mf < 4; mf++)
#pragma unroll
        for (int kk = 0; kk < 2; kk++)
            dst[mf][kk] = *(const bf16x8*)(cb + uoff + mf * 2048 + base[kk]);
}

__device__ __forceinline__ void readB(bf16x8 (&dst)[2][2], const char* cb, int uoff,
                                      const int (&base)[2]) {
#pragma unroll
    for (int nf = 0; nf < 2; nf++)
#pragma unroll
        for (int kk = 0; kk < 2; kk++)
            dst[nf][kk] = *(const bf16x8*)(cb + uoff + nf * 2048 + base[kk]);
}

// MODE 0 (QKV, N=3072): col region uniform per 256-tile:
//   col0<1024 -> Q (scaled); <2048 -> K; else V TRANSPOSED [bh][d][n]
// MODE 2: fp32 row-major [M][N]
template <int MODE, int N>
__global__ __launch_bounds__(512, 2) void gemm8p_kernel(
    const unsigned short* __restrict__ A,
    const unsigned short* __restrict__ BT,
    unsigned short* __restrict__ Cq,
    unsigned short* __restrict__ Ck,
    unsigned short* __restrict__ Cv,
    float* __restrict__ CF) {
    constexpr int K = 1024;
    __shared__ __align__(16) char smem[131072];

    const int tid  = threadIdx.x;        // 0..511
    const int wid  = tid >> 6;
    const int lane = tid & 63;
    const int g    = lane >> 4;
    const int lr   = lane & 15;
    const int wr   = wid >> 2;           // 0..1  (M half)
    const int wc   = wid & 3;            // 0..3  (N quarter)

    const int nwg = gridDim.x * gridDim.y;
    const int hw  = blockIdx.y * gridDim.x + blockIdx.x;
    const int swz = (hw & 7) * (nwg >> 3) + (hw >> 3);
    const int row0 = (swz / gridDim.x) * 256;
    const int col0 = (swz % gridDim.x) * 256;

    // ---- staging precompute (per thread) ----
    const int rA = tid >> 3;                              // 0..63
    const int l  = (tid & 7) ^ (rA & 7);                  // swizzled k-slot
    const size_t sA  = (size_t)(row0 + rA) * K + l * 8;   // + (u*64+i*128)*K + kt
    const int cb0 = (rA & 31) + ((rA >> 5) << 6);
    const size_t sB  = (size_t)(col0 + cb0) * K + l * 8;  // + (u*32+i*128)*K + kt
    const int ldsStageOff = wid * 1024 + lane * 16;

    // ---- fragment read byte offsets ----
    int aBase[2], bBase[2];
#pragma unroll
    for (int kk = 0; kk < 2; kk++) {
        aBase[kk] = (wr * 64 + lr) * 128 + (((kk * 4 + g) ^ (lr & 7)) * 16);
        bBase[kk] = 32768 + (wc * 32 + lr) * 128 + (((kk * 4 + g) ^ (lr & 7)) * 16);
    }

    f32x4 acc[8][4];
#pragma unroll
    for (int i = 0; i < 8; i++)
#pragma unroll
        for (int j = 0; j < 4; j++) acc[i][j] = f32x4{0.f, 0.f, 0.f, 0.f};

    auto STAGE_A = [&](char* nb, int u, int kt) {
        __builtin_amdgcn_global_load_lds(AS1C(A + sA + (size_t)(u * 64) * K + kt),
                                         AS3(nb + u * 16384 + ldsStageOff), 16, 0, 0);
        __builtin_amdgcn_global_load_lds(AS1C(A + sA + (size_t)(u * 64 + 128) * K + kt),
                                         AS3(nb + u * 16384 + 8192 + ldsStageOff), 16, 0, 0);
    };
    auto STAGE_B = [&](char* nb, int u, int kt) {
        __builtin_amdgcn_global_load_lds(AS1C(BT + sB + (size_t)(u * 32) * K + kt),
                                         AS3(nb + 32768 + u * 16384 + ldsStageOff), 16, 0, 0);
        __builtin_amdgcn_global_load_lds(AS1C(BT + sB + (size_t)(u * 32 + 128) * K + kt),
                                         AS3(nb + 32768 + u * 16384 + 8192 + ldsStageOff), 16, 0, 0);
    };

    bf16x8 a1[4][2], a2[4][2], b1[2][2], b2[2][2];

    // ---- prologue: stage tile 0 (A1,B1,A2,B2), confirm A1,B1, pre-read ----
    STAGE_A(smem, 0, 0);
    STAGE_B(smem, 0, 0);
    STAGE_A(smem, 1, 0);
    STAGE_B(smem, 1, 0);
    asm volatile("s_waitcnt vmcnt(4)" ::: "memory");
    __builtin_amdgcn_s_barrier();
    readA(a1, smem, 0, aBase);
    readB(b1, smem, 0, bBase);

    const int NT = K / 64;                 // 16
    int cur = 0;
    for (int t = 0; t < NT; t++) {
        char* cbuf = smem + cur * 65536;
        char* nbuf = smem + (cur ^ 1) * 65536;
        const int ktn  = (t + 1) * 64;
        const bool more = (t + 1 < NT);

        // Ph1: stage A1(t+1) | confirm A2(t) | read a2(t) | Q1 = a1 x b1
        if (more) {
            STAGE_A(nbuf, 0, ktn);
            asm volatile("s_waitcnt vmcnt(4)" ::: "memory");
        } else {
            asm volatile("s_waitcnt vmcnt(2)" ::: "memory");
        }
        __builtin_amdgcn_s_barrier();
        readA(a2, cbuf, 16384, aBase);
        quad<0, 0>(acc, a1, b1);
        __builtin_amdgcn_s_barrier();

        // Ph2: stage B1(t+1) | confirm B2(t) | read b2(t) | Q2 = a2 x b1
        if (more) {
            STAGE_B(nbuf, 0, ktn);
            asm volatile("s_waitcnt vmcnt(4)" ::: "memory");
        } else {
            asm volatile("s_waitcnt vmcnt(0)" ::: "memory");
        }
        __builtin_amdgcn_s_barrier();
        readB(b2, cbuf, 16384, bBase);
        quad<4, 0>(acc, a2, b1);
        __builtin_amdgcn_s_barrier();

        // Ph3: stage A2(t+1) | Q3 = a1 x b2  (no wait, no reads)
        if (more) STAGE_A(nbuf, 1, ktn);
        __builtin_amdgcn_s_barrier();
        quad<0, 2>(acc, a1, b2);
        __builtin_amdgcn_s_barrier();

        // Ph4: stage B2(t+1) | confirm A1,B1(t+1) | read a1,b1(t+1) | Q4
        if (more) {
            STAGE_B(nbuf, 1, ktn);
            asm volatile("s_waitcnt vmcnt(4)" ::: "memory");
        }
        __builtin_amdgcn_s_barrier();
        if (more) {
            readA(a1, nbuf, 0, aBase);
            readB(b1, nbuf, 0, bBase);
        }
        quad<4, 2>(acc, a2, b2);
        __builtin_amdgcn_s_barrier();

        cur ^= 1;
    }

    // ---- epilogue ----
    const float SCALE = 0.125f * 1.44269504088896340736f;  // 1/sqrt(dk)*log2e
    const int region = (MODE == 0) ? (col0 >> 10) : 2;     // block-uniform
#pragma unroll
    for (int mf = 0; mf < 8; mf++)
#pragma unroll
        for (int nf = 0; nf < 4; nf++) {
            if (MODE == 2) {
#pragma unroll
                for (int r = 0; r < 4; r++) {
                    int grow = row0 + wr * 128 + mf * 16 + g * 4 + r;
                    int gcol = col0 + wc * 64 + nf * 16 + lr;
                    CF[(size_t)grow * N + gcol] = acc[mf][nf][r];
                }
            } else if (region == 0) {              // Q, scaled
#pragma unroll
                for (int r = 0; r < 4; r++) {
                    int grow = row0 + wr * 128 + mf * 16 + g * 4 + r;
                    int gcol = col0 + wc * 64 + nf * 16 + lr;
                    int b = grow >> 11, n = grow & 2047;
                    int h = gcol >> 6, d = gcol & 63;
                    Cq[(((size_t)(b * 16 + h)) * 2048 + n) * 64 + d] =
                        f2bf(acc[mf][nf][r] * SCALE);
                }
            } else if (region == 1) {              // K
#pragma unroll
                for (int r = 0; r < 4; r++) {
                    int grow = row0 + wr * 128 + mf * 16 + g * 4 + r;
                    int jj   = col0 - 1024 + wc * 64 + nf * 16 + lr;
                    int b = grow >> 11, n = grow & 2047;
                    int h = jj >> 6, d = jj & 63;
                    Ck[(((size_t)(b * 16 + h)) * 2048 + n) * 64 + d] =
                        f2bf(acc[mf][nf][r]);
                }
            } else {                               // V transposed [bh][d][n]
                int jj = col0 - 2048 + wc * 64 + nf * 16 + lr;
                int h  = jj >> 6, d = jj & 63;
                int n0 = row0 + wr * 128 + mf * 16 + g * 4;
                int b  = n0 >> 11, nn = n0 & 2047;
                u16x4 pk;
#pragma unroll
                for (int r = 0; r < 4; r++) pk[r] = f2bf(acc[mf][nf][r]);
                *(u16x4*)(Cv + (((size_t)(b * 16 + h)) * 64 + d) * 2048 + nn) = pk;
            }
        }
}

// ------------------------------ flash attention ----------------------------
// (unchanged: 4 waves x 32 q-rows, 3-deep counted-vmcnt staging, swapped
// QK^T + permuted keymap, exp-bias in MFMA C-init, ones-MFMA denominator)
__global__ __launch_bounds__(256) void attn_fwd_kernel(
    const unsigned short* __restrict__ Q,
    const unsigned short* __restrict__ K,
    const unsigned short* __restrict__ Vt,
    unsigned short* __restrict__ O) {
    __shared__ __align__(16) char smem[49152];

    const int tid  = threadIdx.x;
    const int wid  = tid >> 6;
    const int lane = tid & 63;
    const int g    = lane >> 4;
    const int lr   = lane & 15;

    const int hw  = blockIdx.y * 16 + blockIdx.x;
    const int swz = (hw & 7) * 128 + (hw >> 3);
    const int bh  = swz >> 4;
    const int b   = bh >> 4;
    const int h   = bh & 15;
    const size_t hb = (size_t)bh * NSEQ * DK;
    const unsigned short* Qh  = Q + hb;
    const unsigned short* Kh  = K + hb;
    const unsigned short* Vth = Vt + hb;           // [64 d][2048 n]
    const int qw = (swz & 15) * 128 + wid * 32;

    const int srow = lane >> 3;
    const int kOff0 = (wid * 8 + srow) * 64 + ((((lane & 7) ^ srow ^ wid) & 7)) * 8;
    const int kOff1 = ((wid + 4) * 8 + srow) * 64 + ((((lane & 7) ^ srow ^ (wid + 4)) & 7)) * 8;
    const int sslot = (lane & 7) ^ srow;
    const int vOff0 = (wid * 8 + srow) * 2048 + sslot * 8;
    const int vOff1 = ((wid + 4) * 8 + srow) * 2048 + sslot * 8;
    const int ldsK0 = wid * 1024 + lane * 16;
    const int ldsK1 = (wid + 4) * 1024 + lane * 16;

    int kByte[2][4];   // [kk][kb]
#pragma unroll
    for (int kk = 0; kk < 2; kk++)
#pragma unroll
        for (int kb = 0; kb < 4; kb++) {
            int row = (lr >> 2) * 8 + (kb >> 1) * 32 + 2 * (lr & 3) + (kb & 1);
            int sl  = (kk * 4 + g) ^ ((row ^ (row >> 3)) & 7);
            kByte[kk][kb] = row * 128 + sl * 16;
        }
    int vByte[2][4];   // [kc][db]
#pragma unroll
    for (int kc = 0; kc < 2; kc++)
#pragma unroll
        for (int db = 0; db < 4; db++) {
            int d  = db * 16 + lr;
            int sl = (kc * 4 + g) ^ (d & 7);
            vByte[kc][db] = 8192 + d * 128 + sl * 16;
        }

    bf16x8 qf[2][2];
#pragma unroll
    for (int qh = 0; qh < 2; qh++)
#pragma unroll
        for (int kk = 0; kk < 2; kk++)
            qf[qh][kk] = *(const bf16x8*)(Qh + (size_t)(qw + qh * 16 + lr) * 64 +
                                          kk * 32 + g * 8);

    const f32x4 M12 = f32x4{-12.f, -12.f, -12.f, -12.f};
    bf16x8 ones;
#pragma unroll
    for (int i = 0; i < 8; i++) ones[i] = (short)0x3F80;   // bf16 1.0

    f32x4 acc_o[2][4], acc_den[2];
#pragma unroll
    for (int qh = 0; qh < 2; qh++) {
        acc_den[qh] = f32x4{0.f, 0.f, 0.f, 0.f};
#pragma unroll
        for (int d = 0; d < 4; d++) acc_o[qh][d] = f32x4{0.f, 0.f, 0.f, 0.f};
    }

    auto STAGE = [&](char* buf, int kv0) {
        __builtin_amdgcn_global_load_lds(AS1C(Kh + (size_t)kv0 * 64 + kOff0),
                                         AS3(buf + ldsK0), 16, 0, 0);
        __builtin_amdgcn_global_load_lds(AS1C(Kh + (size_t)kv0 * 64 + kOff1),
                                         AS3(buf + ldsK1), 16, 0, 0);
        __builtin_amdgcn_global_load_lds(AS1C(Vth + kv0 + vOff0),
                                         AS3(buf + 8192 + ldsK0), 16, 0, 0);
        __builtin_amdgcn_global_load_lds(AS1C(Vth + kv0 + vOff1),
                                         AS3(buf + 8192 + ldsK1), 16, 0, 0);
    };

    const int NT = NSEQ / 64;                      // 32
    char* b0 = smem;
    char* b1 = smem + 16384;
    char* b2 = smem + 32768;
    STAGE(b0, 0);
    STAGE(b1, 64);

    for (int kvt = 0; kvt < NT; kvt++) {
        if (kvt < NT - 1) asm volatile("s_waitcnt vmcnt(4)" ::: "memory");
        else              asm volatile("s_waitcnt vmcnt(0)" ::: "memory");
        __builtin_amdgcn_s_barrier();
        if (kvt + 2 < NT) STAGE(b2, (kvt + 2) * 64);

        bf16x8 pa[2][2];              // [qh][kc]
#pragma unroll
        for (int kc = 0; kc < 2; kc++) {
            bf16x8 kf00 = *(const bf16x8*)(b0 + kByte[0][kc * 2 + 0]);
            bf16x8 kf01 = *(const bf16x8*)(b0 + kByte[0][kc * 2 + 1]);
            bf16x8 kf10 = *(const bf16x8*)(b0 + kByte[1][kc * 2 + 0]);
            bf16x8 kf11 = *(const bf16x8*)(b0 + kByte[1][kc * 2 + 1]);
            f32x4 s00 = __builtin_amdgcn_mfma_f32_16x16x32_bf16(kf00, qf[0][0], M12, 0, 0, 0);
            s00       = __builtin_amdgcn_mfma_f32_16x16x32_bf16(kf10, qf[0][1], s00, 0, 0, 0);
            f32x4 s01 = __builtin_amdgcn_mfma_f32_16x16x32_bf16(kf01, qf[0][0], M12, 0, 0, 0);
            s01       = __builtin_amdgcn_mfma_f32_16x16x32_bf16(kf11, qf[0][1], s01, 0, 0, 0);
            f32x4 s10 = __builtin_amdgcn_mfma_f32_16x16x32_bf16(kf00, qf[1][0], M12, 0, 0, 0);
            s10       = __builtin_amdgcn_mfma_f32_16x16x32_bf16(kf10, qf[1][1], s10, 0, 0, 0);
            f32x4 s11 = __builtin_amdgcn_mfma_f32_16x16x32_bf16(kf01, qf[1][0], M12, 0, 0, 0);
            s11       = __builtin_amdgcn_mfma_f32_16x16x32_bf16(kf11, qf[1][1], s11, 0, 0, 0);
#pragma unroll
            for (int qh = 0; qh < 2; qh++) {
                const f32x4& sA = qh ? s10 : s00;
                const f32x4& sB = qh ? s11 : s01;
                float p0[4], p1[4];
#pragma unroll
                for (int r = 0; r < 4; r++) {
                    float e0, e1;
                    asm("v_exp_f32 %0, %1" : "=v"(e0) : "v"(sA[r]));
                    asm("v_exp_f32 %0, %1" : "=v"(e1) : "v"(sB[r]));
                    p0[r] = e0; p1[r] = e1;
                }
                union { unsigned int w[4]; bf16x8 v; } u;
#pragma unroll
                for (int t = 0; t < 4; t++) {
                    unsigned int w;
                    asm("v_cvt_pk_bf16_f32 %0, %1, %2"
                        : "=v"(w) : "v"(p0[t]), "v"(p1[t]));
                    u.w[t] = w;
                }
                pa[qh][kc] = u.v;
            }
        }

#pragma unroll
        for (int qh = 0; qh < 2; qh++) {
            acc_den[qh] = __builtin_amdgcn_mfma_f32_16x16x32_bf16(pa[qh][0], ones, acc_den[qh], 0, 0, 0);
            acc_den[qh] = __builtin_amdgcn_mfma_f32_16x16x32_bf16(pa[qh][1], ones, acc_den[qh], 0, 0, 0);
        }

#pragma unroll
        for (int kc = 0; kc < 2; kc++)
#pragma unroll
            for (int db = 0; db < 4; db++) {
                bf16x8 vf = *(const bf16x8*)(b0 + vByte[kc][db]);
                acc_o[0][db] = __builtin_amdgcn_mfma_f32_16x16x32_bf16(pa[0][kc], vf, acc_o[0][db], 0, 0, 0);
                acc_o[1][db] = __builtin_amdgcn_mfma_f32_16x16x32_bf16(pa[1][kc], vf, acc_o[1][db], 0, 0, 0);
            }

        char* tmp = b0; b0 = b1; b1 = b2; b2 = tmp;
    }

#pragma unroll
    for (int qh = 0; qh < 2; qh++) {
        float inv[4];
#pragma unroll
        for (int r = 0; r < 4; r++) {
            float iv;
            asm("v_rcp_f32 %0, %1" : "=v"(iv) : "v"(acc_den[qh][r]));
            inv[r] = iv;
        }
#pragma unroll
        for (int r = 0; r < 4; r++) {
            int n       = qw + qh * 16 + g * 4 + r;
            size_t base = ((size_t)(b * NSEQ + n)) * DMODEL + h * 64;
#pragma unroll
            for (int db = 0; db < 4; db++)
                O[base + db * 16 + lr] = f2bf(acc_o[qh][db][r] * inv[r]);
        }
    }
}

// --------------------------------- launcher --------------------------------

extern "C" void kernel_launch(void* const* d_in, const int* in_sizes, int n_in,
                              void* d_out, int out_size, void* d_ws, size_t ws_size,
                              hipStream_t stream) {
    const float* x   = (const float*)d_in[0];
    const float* Wq  = (const float*)d_in[1];
    const float* Wkv = (const float*)d_in[2];
    const float* Wo  = (const float*)d_in[3];
    float* out       = (float*)d_out;

    char* ws = (char*)d_ws;
    unsigned short* xb     = (unsigned short*)(ws);                     // 16 MB
    unsigned short* WqkvT  = (unsigned short*)(ws + (16u << 20));       // 6 MB [3072][1024]
    unsigned short* WoT    = (unsigned short*)(ws + (22u << 20));       // 2 MB
    unsigned short* Qb     = (unsigned short*)(ws + (24u << 20));       // 16 MB
    unsigned short* Kb     = (unsigned short*)(ws + (40u << 20));       // 16 MB
    unsigned short* Vbt    = (unsigned short*)(ws + (56u << 20));       // 16 MB [bh][64][2048]
    unsigned short* Ob     = xb;   // reuse: xb dead after QKV projection
    if (ws_size < (72u << 20)) return;   // insufficient scratch: fail visibly

    cvt_x_kernel<<<8192, 256, 0, stream>>>((const float4*)x, (u16x4*)xb);
    transpose_cvt_kernel<<<dim3(32, 32), dim3(32, 8), 0, stream>>>(Wq, WqkvT, 1024, 1024);
    transpose_cvt_kernel<<<dim3(64, 32), dim3(32, 8), 0, stream>>>(Wkv, WqkvT + (1024u * 1024u), 1024, 2048);
    transpose_cvt_kernel<<<dim3(32, 32), dim3(32, 8), 0, stream>>>(Wo, WoT, 1024, 1024);

    // merged QKV projection: N = 3072 (Q | K | V^T), 8-phase 256x256
    gemm8p_kernel<0, 3072><<<dim3(12, 32), 512, 0, stream>>>(xb, WqkvT, Qb, Kb, Vbt, nullptr);
    attn_fwd_kernel<<<dim3(16, 64), 256, 0, stream>>>(Qb, Kb, Vbt, Ob);
    gemm8p_kernel<2, 1024><<<dim3(4, 32), 512, 0, stream>>>(Ob, WoT, nullptr, nullptr, nullptr, out);
}

// Round 10
// 253.714 us; speedup vs baseline: 1.1038x; 1.1038x over previous
//
#include <hip/hip_runtime.h>
#include <stdint.h>

// ---------------------------------------------------------------------------
// MultiHeadAttention fwd: out = softmax((xWq)(xWk)^T / 8) (xWv) @ Wo
// B=4, N=2048, H=16, Dk=64, Dmodel=1024.  bf16 MFMA 16x16x32 everywhere.
// R10: GEMMs reverted to R6's proven 3-deep BK=32 128x128 pipeline (best
// measured).  Attn: 64 q-rows/wave (4 q-halves share every K/V ds_read ->
// LDS traffic per q halved), 512-block grid = exactly 2 blocks/CU, 1 gen.
// ---------------------------------------------------------------------------

#define NSEQ   2048
#define BQ     4
#define NTOK   (BQ * NSEQ)      // 8192
#define DMODEL 1024
#define DK     64
#define HEADS  16

using bf16x8 = __attribute__((ext_vector_type(8))) short;           // 8 bf16 raw
using u16x8  = __attribute__((ext_vector_type(8))) unsigned short;
using u16x4  = __attribute__((ext_vector_type(4))) unsigned short;
using f32x4  = __attribute__((ext_vector_type(4))) float;

#define AS1C(p) ((const __attribute__((address_space(1))) void*)(p))
#define AS3(p)  ((__attribute__((address_space(3))) void*)(p))

__device__ __forceinline__ unsigned short f2bf(float f) {
    unsigned int u = __float_as_uint(f);
    u += 0x7FFFu + ((u >> 16) & 1u);     // RNE
    return (unsigned short)(u >> 16);
}

// ------------------------------- conversions -------------------------------

__global__ __launch_bounds__(256) void cvt_x_kernel(const float4* __restrict__ in,
                                                    u16x4* __restrict__ out) {
    int idx = blockIdx.x * 256 + threadIdx.x;   // exact: 8192*256*4 == 8.39M
    float4 v = in[idx];
    u16x4 o;
    o[0] = f2bf(v.x); o[1] = f2bf(v.y); o[2] = f2bf(v.z); o[3] = f2bf(v.w);
    out[idx] = o;
}

// in: fp32 [K][Nn] row-major  ->  out: bf16 [Nn][K] row-major (i.e. W^T)
__global__ __launch_bounds__(256) void transpose_cvt_kernel(const float* __restrict__ in,
                                                            unsigned short* __restrict__ out,
                                                            int K, int Nn) {
    __shared__ float t[32][33];
    int c0 = blockIdx.x * 32;     // Nn tile
    int r0 = blockIdx.y * 32;     // K tile
    int tx = threadIdx.x;         // 0..31
    int ty = threadIdx.y;         // 0..7
#pragma unroll
    for (int i = 0; i < 4; i++) {
        int r = ty + i * 8;
        t[r][tx] = in[(size_t)(r0 + r) * Nn + c0 + tx];
    }
    __syncthreads();
#pragma unroll
    for (int i = 0; i < 4; i++) {
        int r = ty + i * 8;
        out[(size_t)(c0 + r) * K + r0 + tx] = f2bf(t[tx][r]);
    }
}

// ----------------------------------- GEMM ----------------------------------
// (R6 proven structure) C[M,N] = A[M,K] * BT[N,K]^T, 128x128 tile, BK=32,
// 4 waves (2x2), 3-deep LDS pipeline (3 x 16KB), counted vmcnt(4), single
// s_barrier per K-step.  LDS row j (128B, 8 slots) holds tile-rows j and
// j+64 (64B each); logical slot l = h*4+kgroup, physical = l ^ (j&7).
// MODE 0 (merged QKV, N=3072): col region uniform per block:
//   col0<1024 -> Q (scaled); <2048 -> K; else V TRANSPOSED [bh][d][n]
// MODE 2: fp32 row-major [M][N]
template <int MODE>
__global__ __launch_bounds__(256) void gemm_bf16_kernel(
    const unsigned short* __restrict__ A,
    const unsigned short* __restrict__ BT,
    unsigned short* __restrict__ Cq,
    unsigned short* __restrict__ Ck,
    unsigned short* __restrict__ Cv,
    float* __restrict__ CF,
    int M, int N, int K) {
    __shared__ __align__(16) char smem[49152];   // 3 bufs x (A 8K | B 8K)

    const int tid  = threadIdx.x;
    const int wid  = tid >> 6;
    const int lane = tid & 63;
    const int g    = lane >> 4;
    const int lr   = lane & 15;
    const int wr   = wid >> 1;
    const int wc   = wid & 1;

    // XCD-aware bijective swizzle (nwg % 8 == 0 for all our grids)
    const int nwg = gridDim.x * gridDim.y;
    const int hw  = blockIdx.y * gridDim.x + blockIdx.x;
    const int swz = (hw & 7) * (nwg >> 3) + (hw >> 3);
    const int row0 = (swz / gridDim.x) * 128;
    const int col0 = (swz % gridDim.x) * 128;

    const int lsw  = (lane & 7) ^ (lane >> 3);
    int srcOff[2], ldsOff[2];
#pragma unroll
    for (int i = 0; i < 2; i++) {
        int ch = wid + 4 * i;
        int j  = ch * 8 + (lane >> 3);
        srcOff[i] = (j + 64 * (lsw >> 2)) * K + (lsw & 3) * 8;
        ldsOff[i] = ch * 1024 + lane * 16;
    }

    int aByte[4], bByte[4];
#pragma unroll
    for (int f = 0; f < 4; f++) {
        int ja = f * 16 + lr;
        aByte[f] = ja * 128 + (((wr * 4 + g) ^ (ja & 7)) * 16);
        int jb = f * 16 + lr;
        bByte[f] = 8192 + jb * 128 + (((wc * 4 + g) ^ (jb & 7)) * 16);
    }

    f32x4 acc[4][4];
#pragma unroll
    for (int i = 0; i < 4; i++)
#pragma unroll
        for (int j = 0; j < 4; j++) acc[i][j] = f32x4{0.f, 0.f, 0.f, 0.f};

    auto STAGE = [&](char* buf, int kt) {
#pragma unroll
        for (int i = 0; i < 2; i++)
            __builtin_amdgcn_global_load_lds(
                AS1C(A + (size_t)row0 * K + kt + srcOff[i]),
                AS3(buf + ldsOff[i]), 16, 0, 0);
#pragma unroll
        for (int i = 0; i < 2; i++)
            __builtin_amdgcn_global_load_lds(
                AS1C(BT + (size_t)col0 * K + kt + srcOff[i]),
                AS3(buf + 8192 + ldsOff[i]), 16, 0, 0);
    };

    const int NT = K >> 5;                        // BK = 32
    char* b0 = smem;
    char* b1 = smem + 16384;
    char* b2 = smem + 32768;
    STAGE(b0, 0);
    STAGE(b1, 32);

    for (int t = 0; t < NT; t++) {
        if (t < NT - 1) asm volatile("s_waitcnt vmcnt(4)" ::: "memory");
        else            asm volatile("s_waitcnt vmcnt(0)" ::: "memory");
        __builtin_amdgcn_s_barrier();
        if (t + 2 < NT) STAGE(b2, (t + 2) * 32);

        bf16x8 af[4], bfr[4];
#pragma unroll
        for (int f = 0; f < 4; f++) af[f]  = *(const bf16x8*)(b0 + aByte[f]);
#pragma unroll
        for (int f = 0; f < 4; f++) bfr[f] = *(const bf16x8*)(b0 + bByte[f]);
#pragma unroll
        for (int mf = 0; mf < 4; mf++)
#pragma unroll
            for (int nf = 0; nf < 4; nf++)
                acc[mf][nf] = __builtin_amdgcn_mfma_f32_16x16x32_bf16(
                    af[mf], bfr[nf], acc[mf][nf], 0, 0, 0);

        char* tmp = b0; b0 = b1; b1 = b2; b2 = tmp;
    }

    const float SCALE = 0.125f * 1.44269504088896340736f;  // 1/sqrt(dk)*log2e
    const int region = (MODE == 0) ? (col0 >> 10) : 2;     // block-uniform
#pragma unroll
    for (int mf = 0; mf < 4; mf++)
#pragma unroll
        for (int nf = 0; nf < 4; nf++) {
            if (MODE == 2) {
#pragma unroll
                for (int r = 0; r < 4; r++) {
                    int grow = row0 + wr * 64 + mf * 16 + g * 4 + r;
                    int gcol = col0 + wc * 64 + nf * 16 + lr;
                    CF[(size_t)grow * N + gcol] = acc[mf][nf][r];
                }
            } else if (region == 0) {              // Q, scaled
#pragma unroll
                for (int r = 0; r < 4; r++) {
                    int grow = row0 + wr * 64 + mf * 16 + g * 4 + r;
                    int gcol = col0 + wc * 64 + nf * 16 + lr;
                    int b = grow >> 11, n = grow & 2047;
                    int h = gcol >> 6, d = gcol & 63;
                    Cq[(((size_t)(b * 16 + h)) * 2048 + n) * 64 + d] =
                        f2bf(acc[mf][nf][r] * SCALE);
                }
            } else if (region == 1) {              // K
#pragma unroll
                for (int r = 0; r < 4; r++) {
                    int grow = row0 + wr * 64 + mf * 16 + g * 4 + r;
                    int jj   = col0 - 1024 + wc * 64 + nf * 16 + lr;
                    int b = grow >> 11, n = grow & 2047;
                    int h = jj >> 6, d = jj & 63;
                    Ck[(((size_t)(b * 16 + h)) * 2048 + n) * 64 + d] =
                        f2bf(acc[mf][nf][r]);
                }
            } else {                               // V transposed [bh][d][n]
                int jj = col0 - 2048 + wc * 64 + nf * 16 + lr;
                int h  = jj >> 6, d = jj & 63;
                int n0 = row0 + wr * 64 + mf * 16 + g * 4;
                int b  = n0 >> 11, nn = n0 & 2047;
                u16x4 pk;
#pragma unroll
                for (int r = 0; r < 4; r++) pk[r] = f2bf(acc[mf][nf][r]);
                *(u16x4*)(Cv + (((size_t)(b * 16 + h)) * 64 + d) * 2048 + nn) = pk;
            }
        }
}

// ------------------------------ flash attention ----------------------------
// grid (8, 64): 4 waves x 64 q-rows (4 q-halves share every kf/vf ds_read
// -> LDS bytes per q HALVED vs 32q/wave).  512 blocks = 2/CU exactly.
// KVBLK=64, 3-deep staging (3 x (K 8K | V 8K) = 48KB), counted vmcnt(4).
// SWAPPED QK^T, PERMUTED KEYMAP (key = 8a + 32(kb>>1) + 2r + (kb&1)) ->
// P->PA pure in-register cvt_pk.  exp bias -12 in MFMA C-init; denominator
// via ones-MFMA.  kc-major loop: read 4 kf + 4 vf once per kc, then 4
// independent qh chains (QK->exp->cvt->den->PV) give the scheduler ILP.
__global__ __launch_bounds__(256) void attn_fwd_kernel(
    const unsigned short* __restrict__ Q,
    const unsigned short* __restrict__ K,
    const unsigned short* __restrict__ Vt,
    unsigned short* __restrict__ O) {
    __shared__ __align__(16) char smem[49152];

    const int tid  = threadIdx.x;
    const int wid  = tid >> 6;
    const int lane = tid & 63;
    const int g    = lane >> 4;
    const int lr   = lane & 15;

    // XCD swizzle: 512 blocks; consecutive swz share bh -> same-XCD KV reuse
    const int hw  = blockIdx.y * 8 + blockIdx.x;
    const int swz = (hw & 7) * 64 + (hw >> 3);
    const int bh  = swz >> 3;
    const int b   = bh >> 4;
    const int h   = bh & 15;
    const size_t hb = (size_t)bh * NSEQ * DK;
    const unsigned short* Qh  = Q + hb;
    const unsigned short* Kh  = K + hb;
    const unsigned short* Vth = Vt + hb;           // [64 d][2048 n]
    const int qw = (swz & 7) * 256 + wid * 64;

    const int srow = lane >> 3;
    const int kOff0 = (wid * 8 + srow) * 64 + ((((lane & 7) ^ srow ^ wid) & 7)) * 8;
    const int kOff1 = ((wid + 4) * 8 + srow) * 64 + ((((lane & 7) ^ srow ^ (wid + 4)) & 7)) * 8;
    const int sslot = (lane & 7) ^ srow;
    const int vOff0 = (wid * 8 + srow) * 2048 + sslot * 8;
    const int vOff1 = ((wid + 4) * 8 + srow) * 2048 + sslot * 8;
    const int ldsK0 = wid * 1024 + lane * 16;
    const int ldsK1 = (wid + 4) * 1024 + lane * 16;

    int kByte[2][4];   // [kk][kb]
#pragma unroll
    for (int kk = 0; kk < 2; kk++)
#pragma unroll
        for (int kb = 0; kb < 4; kb++) {
            int row = (lr >> 2) * 8 + (kb >> 1) * 32 + 2 * (lr & 3) + (kb & 1);
            int sl  = (kk * 4 + g) ^ ((row ^ (row >> 3)) & 7);
            kByte[kk][kb] = row * 128 + sl * 16;
        }
    int vByte[2][4];   // [kc][db]
#pragma unroll
    for (int kc = 0; kc < 2; kc++)
#pragma unroll
        for (int db = 0; db < 4; db++) {
            int d  = db * 16 + lr;
            int sl = (kc * 4 + g) ^ (d & 7);
            vByte[kc][db] = 8192 + d * 128 + sl * 16;
        }

    // Q fragments (B-operand): qf[qh][kk] = Q[qw+qh*16+lr][kk*32+g*8 ..]
    bf16x8 qf[4][2];
#pragma unroll
    for (int qh = 0; qh < 4; qh++)
#pragma unroll
        for (int kk = 0; kk < 2; kk++)
            qf[qh][kk] = *(const bf16x8*)(Qh + (size_t)(qw + qh * 16 + lr) * 64 +
                                          kk * 32 + g * 8);

    const f32x4 M12 = f32x4{-12.f, -12.f, -12.f, -12.f};
    bf16x8 ones;
#pragma unroll
    for (int i = 0; i < 8; i++) ones[i] = (short)0x3F80;   // bf16 1.0

    f32x4 acc_o[4][4], acc_den[4];
#pragma unroll
    for (int qh = 0; qh < 4; qh++) {
        acc_den[qh] = f32x4{0.f, 0.f, 0.f, 0.f};
#pragma unroll
        for (int d = 0; d < 4; d++) acc_o[qh][d] = f32x4{0.f, 0.f, 0.f, 0.f};
    }

    auto STAGE = [&](char* buf, int kv0) {
        __builtin_amdgcn_global_load_lds(AS1C(Kh + (size_t)kv0 * 64 + kOff0),
                                         AS3(buf + ldsK0), 16, 0, 0);
        __builtin_amdgcn_global_load_lds(AS1C(Kh + (size_t)kv0 * 64 + kOff1),
                                         AS3(buf + ldsK1), 16, 0, 0);
        __builtin_amdgcn_global_load_lds(AS1C(Vth + kv0 + vOff0),
                                         AS3(buf + 8192 + ldsK0), 16, 0, 0);
        __builtin_amdgcn_global_load_lds(AS1C(Vth + kv0 + vOff1),
                                         AS3(buf + 8192 + ldsK1), 16, 0, 0);
    };

    const int NT = NSEQ / 64;                      // 32
    char* b0 = smem;
    char* b1 = smem + 16384;
    char* b2 = smem + 32768;
    STAGE(b0, 0);
    STAGE(b1, 64);

    for (int kvt = 0; kvt < NT; kvt++) {
        if (kvt < NT - 1) asm volatile("s_waitcnt vmcnt(4)" ::: "memory");
        else              asm volatile("s_waitcnt vmcnt(0)" ::: "memory");
        __builtin_amdgcn_s_barrier();
        if (kvt + 2 < NT) STAGE(b2, (kvt + 2) * 64);

#pragma unroll
        for (int kc = 0; kc < 2; kc++) {
            // shared reads for this key-chunk: 4 K-frags + 4 V-frags
            bf16x8 kf00 = *(const bf16x8*)(b0 + kByte[0][kc * 2 + 0]);
            bf16x8 kf01 = *(const bf16x8*)(b0 + kByte[0][kc * 2 + 1]);
            bf16x8 kf10 = *(const bf16x8*)(b0 + kByte[1][kc * 2 + 0]);
            bf16x8 kf11 = *(const bf16x8*)(b0 + kByte[1][kc * 2 + 1]);
            bf16x8 vf0  = *(const bf16x8*)(b0 + vByte[kc][0]);
            bf16x8 vf1  = *(const bf16x8*)(b0 + vByte[kc][1]);
            bf16x8 vf2  = *(const bf16x8*)(b0 + vByte[kc][2]);
            bf16x8 vf3  = *(const bf16x8*)(b0 + vByte[kc][3]);
#pragma unroll
            for (int qh = 0; qh < 4; qh++) {
                f32x4 s0 = __builtin_amdgcn_mfma_f32_16x16x32_bf16(kf00, qf[qh][0], M12, 0, 0, 0);
                s0       = __builtin_amdgcn_mfma_f32_16x16x32_bf16(kf10, qf[qh][1], s0, 0, 0, 0);
                f32x4 s1 = __builtin_amdgcn_mfma_f32_16x16x32_bf16(kf01, qf[qh][0], M12, 0, 0, 0);
                s1       = __builtin_amdgcn_mfma_f32_16x16x32_bf16(kf11, qf[qh][1], s1, 0, 0, 0);
                float p0[4], p1[4];
#pragma unroll
                for (int r = 0; r < 4; r++) {
                    float e0, e1;
                    asm("v_exp_f32 %0, %1" : "=v"(e0) : "v"(s0[r]));
                    asm("v_exp_f32 %0, %1" : "=v"(e1) : "v"(s1[r]));
                    p0[r] = e0; p1[r] = e1;
                }
                union { unsigned int w[4]; bf16x8 v; } u;
#pragma unroll
                for (int t = 0; t < 4; t++) {
                    unsigned int w;
                    asm("v_cvt_pk_bf16_f32 %0, %1, %2"
                        : "=v"(w) : "v"(p0[t]), "v"(p1[t]));
                    u.w[t] = w;
                }
                bf16x8 pa = u.v;
                acc_den[qh] = __builtin_amdgcn_mfma_f32_16x16x32_bf16(pa, ones, acc_den[qh], 0, 0, 0);
                acc_o[qh][0] = __builtin_amdgcn_mfma_f32_16x16x32_bf16(pa, vf0, acc_o[qh][0], 0, 0, 0);
                acc_o[qh][1] = __builtin_amdgcn_mfma_f32_16x16x32_bf16(pa, vf1, acc_o[qh][1], 0, 0, 0);
                acc_o[qh][2] = __builtin_amdgcn_mfma_f32_16x16x32_bf16(pa, vf2, acc_o[qh][2], 0, 0, 0);
                acc_o[qh][3] = __builtin_amdgcn_mfma_f32_16x16x32_bf16(pa, vf3, acc_o[qh][3], 0, 0, 0);
            }
        }

        char* tmp = b0; b0 = b1; b1 = b2; b2 = tmp;
    }

    // epilogue: O[q][d] / den[q]; acc_den[qh][r] is den(q=g*4+r) in ALL lanes
#pragma unroll
    for (int qh = 0; qh < 4; qh++) {
        float inv[4];
#pragma unroll
        for (int r = 0; r < 4; r++) {
            float iv;
            asm("v_rcp_f32 %0, %1" : "=v"(iv) : "v"(acc_den[qh][r]));
            inv[r] = iv;
        }
#pragma unroll
        for (int r = 0; r < 4; r++) {
            int n       = qw + qh * 16 + g * 4 + r;
            size_t base = ((size_t)(b * NSEQ + n)) * DMODEL + h * 64;
#pragma unroll
            for (int db = 0; db < 4; db++)
                O[base + db * 16 + lr] = f2bf(acc_o[qh][db][r] * inv[r]);
        }
    }
}

// --------------------------------- launcher --------------------------------

extern "C" void kernel_launch(void* const* d_in, const int* in_sizes, int n_in,
                              void* d_out, int out_size, void* d_ws, size_t ws_size,
                              hipStream_t stream) {
    const float* x   = (const float*)d_in[0];
    const float* Wq  = (const float*)d_in[1];
    const float* Wkv = (const float*)d_in[2];
    const float* Wo  = (const float*)d_in[3];
    float* out       = (float*)d_out;

    char* ws = (char*)d_ws;
    unsigned short* xb     = (unsigned short*)(ws);                     // 16 MB
    unsigned short* WqkvT  = (unsigned short*)(ws + (16u << 20));       // 6 MB [3072][1024]
    unsigned short* WoT    = (unsigned short*)(ws + (22u << 20));       // 2 MB
    unsigned short* Qb     = (unsigned short*)(ws + (24u << 20));       // 16 MB
    unsigned short* Kb     = (unsigned short*)(ws + (40u << 20));       // 16 MB
    unsigned short* Vbt    = (unsigned short*)(ws + (56u << 20));       // 16 MB [bh][64][2048]
    unsigned short* Ob     = xb;   // reuse: xb dead after QKV projection
    if (ws_size < (72u << 20)) return;   // insufficient scratch: fail visibly

    cvt_x_kernel<<<8192, 256, 0, stream>>>((const float4*)x, (u16x4*)xb);
    transpose_cvt_kernel<<<dim3(32, 32), dim3(32, 8), 0, stream>>>(Wq, WqkvT, 1024, 1024);
    transpose_cvt_kernel<<<dim3(64, 32), dim3(32, 8), 0, stream>>>(Wkv, WqkvT + (1024u * 1024u), 1024, 2048);
    transpose_cvt_kernel<<<dim3(32, 32), dim3(32, 8), 0, stream>>>(Wo, WoT, 1024, 1024);

    // merged QKV projection: N = 3072 (Q | K | V^T)
    gemm_bf16_kernel<0><<<dim3(24, 64), 256, 0, stream>>>(xb, WqkvT, Qb, Kb, Vbt,
                                                          nullptr, NTOK, 3072, 1024);
    attn_fwd_kernel<<<dim3(8, 64), 256, 0, stream>>>(Qb, Kb, Vbt, Ob);
    gemm_bf16_kernel<2><<<dim3(8, 64), 256, 0, stream>>>(Ob, WoT, nullptr, nullptr, nullptr,
                                                         out, NTOK, 1024, 1024);
}